// Round 10
// baseline (224.813 us; speedup 1.0000x reference)
//
#include <hip/hip_runtime.h>
#include <hip/hip_bf16.h>
#include <stdint.h>
#include <stddef.h>

typedef int i32x4 __attribute__((ext_vector_type(4)));

#define B_DIM 8192
#define K_DIM 4096
#define N_DIM 4096

typedef __attribute__((address_space(1))) const void gvoid_t;
typedef __attribute__((address_space(3))) void lvoid_t;

__device__ __forceinline__ void gload_lds16(const void* g, void* l) {
  // width-16 global->LDS DMA; LDS dest is wave-uniform base + lane*16
  __builtin_amdgcn_global_load_lds((gvoid_t*)g, (lvoid_t*)l, 16, 0, 0);
}

#define FENCE() asm volatile("" ::: "memory")
#define BARRIER() do { FENCE(); __builtin_amdgcn_s_barrier(); FENCE(); } while (0)

__device__ __forceinline__ int q8(float v, float inv) {
  float f = v * inv;
  f = fminf(fmaxf(f, -127.f), 127.f);
  return __float2int_rn(f) & 0xff;
}

// ------- kernel 1 (merged prep): row L2-norm + int8 quant for x; int8 quant W
__global__ __launch_bounds__(256) void prep_kernel(
    const float* __restrict__ x, const float* __restrict__ W,
    int8_t* __restrict__ xq, int8_t* __restrict__ wq,
    float* __restrict__ sa, float* __restrict__ sw) {
  const int t = threadIdx.x;
  const int lane = t & 63, wv = t >> 6;
  __shared__ float wsum[4], wamax[4];
  __shared__ float s_inv;

  if (blockIdx.x < B_DIM) {
    const int row = blockIdx.x;
    const float4* xr = (const float4*)(x + (size_t)row * K_DIM);
    float4 v[4];
    float ss = 0.f, am = 0.f;
#pragma unroll
    for (int i = 0; i < 4; ++i) {
      v[i] = xr[i * 256 + t];
      ss += v[i].x * v[i].x + v[i].y * v[i].y + v[i].z * v[i].z + v[i].w * v[i].w;
      am = fmaxf(am, fmaxf(fmaxf(fabsf(v[i].x), fabsf(v[i].y)),
                           fmaxf(fabsf(v[i].z), fabsf(v[i].w))));
    }
#pragma unroll
    for (int o = 32; o > 0; o >>= 1) {
      ss += __shfl_down(ss, o, 64);
      am = fmaxf(am, __shfl_down(am, o, 64));
    }
    if (lane == 0) { wsum[wv] = ss; wamax[wv] = am; }
    __syncthreads();
    if (t == 0) {
      float s = wsum[0] + wsum[1] + wsum[2] + wsum[3];
      float a = fmaxf(fmaxf(wamax[0], wamax[1]), fmaxf(wamax[2], wamax[3]));
      a = fmaxf(a, 1e-20f);
      float sc = 1.0f / (sqrtf(s) + 1e-4f);
      s_inv = 127.0f / a;            // quantization multiplier
      sa[row] = a * sc / 127.0f;     // dequant scale (includes row norm)
    }
    __syncthreads();
    const float inv = s_inv;
    uint32_t* orow = (uint32_t*)(xq + (size_t)row * K_DIM);
#pragma unroll
    for (int i = 0; i < 4; ++i) {
      uint32_t p = (uint32_t)q8(v[i].x, inv) | ((uint32_t)q8(v[i].y, inv) << 8) |
                   ((uint32_t)q8(v[i].z, inv) << 16) | ((uint32_t)q8(v[i].w, inv) << 24);
      orow[i * 256 + t] = p;
    }
  } else {
    const int row = blockIdx.x - B_DIM;   // W output-channel row
    const float4* wr = (const float4*)(W + (size_t)row * K_DIM);
    float4 v[4];
    float am = 0.f;
#pragma unroll
    for (int i = 0; i < 4; ++i) {
      v[i] = wr[i * 256 + t];
      am = fmaxf(am, fmaxf(fmaxf(fabsf(v[i].x), fabsf(v[i].y)),
                           fmaxf(fabsf(v[i].z), fabsf(v[i].w))));
    }
#pragma unroll
    for (int o = 32; o > 0; o >>= 1) am = fmaxf(am, __shfl_down(am, o, 64));
    if (lane == 0) wamax[wv] = am;
    __syncthreads();
    if (t == 0) {
      float a = fmaxf(fmaxf(wamax[0], wamax[1]), fmaxf(wamax[2], wamax[3]));
      a = fmaxf(a, 1e-20f);
      s_inv = 127.0f / a;
      sw[row] = a / 127.0f;
    }
    __syncthreads();
    const float inv = s_inv;
    uint32_t* orow = (uint32_t*)(wq + (size_t)row * K_DIM);
#pragma unroll
    for (int i = 0; i < 4; ++i) {
      uint32_t p = (uint32_t)q8(v[i].x, inv) | ((uint32_t)q8(v[i].y, inv) << 8) |
                   ((uint32_t)q8(v[i].z, inv) << 16) | ((uint32_t)q8(v[i].w, inv) << 24);
      orow[i * 256 + t] = p;
    }
  }
}

// -------- kernel 2: 128x128 int8 GEMM, C = (Aq@Wq^T)*sa*sw + b, ReLU --------
// R10: tile halved (BM=BN=128, 256 thr = 4 waves 2Mx2N, per-wave 64x64 out),
// LDS 64 KiB -> TWO blocks/CU = two INDEPENDENT barrier domains per CU. Same
// wave count (8/CU) as R9 but decorrelated phases: while one block drains a
// barrier the other issues MFMA — attacks the ~40% lockstep dead time of the
// single-block 256² config (R9: MfmaUtil 40.5%, ~2300 cyc/iter unexplained).
// Same proven pieces: BK=128 i8 = 128B rows, XOR swizzle byte^=(row&7)<<4
// (0 conflicts), gload_lds16 DMA staging, vmcnt(4) counted gate.
// 2 phases/iter: P1 {read all 16 ops of T_u; stage A(u+1); BAR; MFMA n0-1; BAR}
//                P2 {stage B(u+2); BAR; MFMA n2-3; vmcnt(4); BAR}
// Ledger: all cur reads issue P1, lgkm-drained before P1-MFMA -> P1-end BAR
// orders them before P2's same-buffer B-stage; A(u+1) targets the other
// buffer whose A-region was last read at u-1 P1 (barrier-separated). Gate
// vmcnt(4) at P2-end leaves only B(u+2) in flight -> A(u+1),B(u+1) landed.
__global__ __launch_bounds__(256, 2) void gemm_kernel(
    const int8_t* __restrict__ A, const int8_t* __restrict__ Bm,
    const float* __restrict__ sa, const float* __restrict__ sw,
    const float* __restrict__ bias, float* __restrict__ C) {
  __shared__ __align__(16) char lds[65536];
  const int tid = threadIdx.x;
  const int lane = tid & 63, w = tid >> 6;
  const int wm = w >> 1, wn = w & 1;
  const int hi16 = lane >> 4;   // 0..3 (k-slot)
  const int r16 = lane & 15;

  // XCD-contiguous swizzle (2048 blocks, 2048 % 8 == 0 -> bijective)
  const int bid = blockIdx.x;
  const int sid = (bid & 7) * 256 + (bid >> 3);
  const int mb = sid & 63;      // 64 M-tiles (consecutive sids share B-panel)
  const int nb = sid >> 6;      // 32 N-tiles

  const char* Ag = (const char*)A + (size_t)mb * 128 * K_DIM;
  const char* Bg = (const char*)Bm + (size_t)nb * 128 * K_DIM;

  // stage half-tile (mat 0=A,1=B; half h = rows h*64..h*64+63) of K-tile kt:
  // 8 KB = 2 x gload_lds16/thread. LDS: [buf2][mat2][128 rows][128 B].
  auto STAGE = [&](int mat, int h, int kt) {
    const int rbase = (kt & 1) * 32768 + mat * 16384 + h * 8192;
    const char* gb = (mat == 0 ? Ag : Bg) + (size_t)h * 64 * K_DIM + kt * 128;
#pragma unroll
    for (int i = 0; i < 2; ++i) {
      const int qb = i * 4096 + w * 1024;          // wave-uniform LDS offset
      const int q = qb + lane * 16;                // this lane's linear slot
      const int r = q >> 7;                        // row within half (0..63)
      const int cb = (q & 127) ^ ((r & 7) << 4);   // inverse-swizzled col byte
      gload_lds16(gb + (size_t)r * K_DIM + cb, lds + rbase + qb);
    }
  };
  auto LDA = [&](int m, int kq, int cur) -> i32x4 {
    const int r = wm * 64 + m * 16 + r16;          // 0..127
    const int q = (r << 7) + (kq << 6) + hi16 * 16;
    return *(const i32x4*)(lds + cur * 32768 + (q ^ ((r & 7) << 4)));
  };
  auto LDB = [&](int n, int kq, int cur) -> i32x4 {
    const int r = wn * 64 + n * 16 + r16;          // 0..127
    const int q = (r << 7) + (kq << 6) + hi16 * 16;
    return *(const i32x4*)(lds + cur * 32768 + 16384 + (q ^ ((r & 7) << 4)));
  };

  i32x4 acc[4][4] = {};
  i32x4 af[4][2], bfr[4][2];

  // prologue: A(T0), B(T0), B(T1); leave B(T1)'s 4 loads in flight
  STAGE(0, 0, 0); STAGE(0, 1, 0); STAGE(1, 0, 0); STAGE(1, 1, 0);
  STAGE(1, 0, 1); STAGE(1, 1, 1);
  asm volatile("s_waitcnt vmcnt(4)" ::: "memory");
  BARRIER();

  for (int u = 0; u < 32; ++u) {
    const int cur = u & 1;
    const int un1 = (u + 1) & 31, un2 = (u + 2) & 31;  // wrap: parity kept, dead data
    // ---- P1: read all 16 cur operands; stage A(T_{u+1}); MFMA n0-1
#pragma unroll
    for (int m = 0; m < 4; ++m)
#pragma unroll
      for (int kq = 0; kq < 2; ++kq) af[m][kq] = LDA(m, kq, cur);
#pragma unroll
    for (int n = 0; n < 4; ++n)
#pragma unroll
      for (int kq = 0; kq < 2; ++kq) bfr[n][kq] = LDB(n, kq, cur);
    STAGE(0, 0, un1);
    STAGE(0, 1, un1);
    BARRIER();
    __builtin_amdgcn_s_setprio(1);
#pragma unroll
    for (int kq = 0; kq < 2; ++kq)
#pragma unroll
      for (int m = 0; m < 4; ++m)
#pragma unroll
        for (int n = 0; n < 2; ++n)
          acc[m][n] = __builtin_amdgcn_mfma_i32_16x16x64_i8(af[m][kq], bfr[n][kq], acc[m][n], 0, 0, 0);
    __builtin_amdgcn_s_setprio(0);
    BARRIER();
    // ---- P2: stage B(T_{u+2}); MFMA n2-3; counted gate vmcnt(4)
    STAGE(1, 0, un2);
    STAGE(1, 1, un2);
    BARRIER();
    __builtin_amdgcn_s_setprio(1);
#pragma unroll
    for (int kq = 0; kq < 2; ++kq)
#pragma unroll
      for (int m = 0; m < 4; ++m)
#pragma unroll
        for (int n = 2; n < 4; ++n)
          acc[m][n] = __builtin_amdgcn_mfma_i32_16x16x64_i8(af[m][kq], bfr[n][kq], acc[m][n], 0, 0, 0);
    __builtin_amdgcn_s_setprio(0);
    asm volatile("s_waitcnt vmcnt(4)" ::: "memory");  // leave B(T_{u+2}) in flight only
    BARRIER();
  }

  // epilogue: y = acc * sa[row]*sw[col] + bias, ReLU, fp32 store.
  // C/D map: col=lane&15, row=(lane>>4)*4+j (dtype-independent, m121-128)
  float bv[4], sbn[4];
#pragma unroll
  for (int n = 0; n < 4; ++n) {
    const int col = nb * 128 + wn * 64 + n * 16 + r16;
    bv[n] = bias[col];
    sbn[n] = sw[col];
  }
#pragma unroll
  for (int m = 0; m < 4; ++m) {
    const int row0 = mb * 128 + wm * 64 + m * 16 + hi16 * 4;
#pragma unroll
    for (int j = 0; j < 4; ++j) {
      const float sv = sa[row0 + j];               // uniform per 16-lane group
      float* crow = C + (size_t)(row0 + j) * N_DIM + nb * 128 + wn * 64 + r16;
#pragma unroll
      for (int n = 0; n < 4; ++n)
        crow[n * 16] = fmaxf((float)acc[m][n][j] * (sv * sbn[n]) + bv[n], 0.f);
    }
  }
}

extern "C" void kernel_launch(void* const* d_in, const int* in_sizes, int n_in,
                              void* d_out, int out_size, void* d_ws, size_t ws_size,
                              hipStream_t stream) {
  const float* x = (const float*)d_in[0];
  const float* W = (const float*)d_in[1];
  const float* b = (const float*)d_in[2];
  float* out = (float*)d_out;

  int8_t* xq = (int8_t*)d_ws;                              // 32 MB
  int8_t* wq = xq + (size_t)B_DIM * K_DIM;                 // 16 MB
  float* sa = (float*)(wq + (size_t)N_DIM * K_DIM);        // 32 KB
  float* sw = sa + B_DIM;                                  // 16 KB

  // 8192 x-rows + 4096 W-rows, one block each
  prep_kernel<<<B_DIM + N_DIM, 256, 0, stream>>>(x, W, xq, wq, sa, sw);
  gemm_kernel<<<64 * 32, 256, 0, stream>>>(xq, wq, sa, sw, b, out);
}

// Round 11
// 196.252 us; speedup vs baseline: 1.1455x; 1.1455x over previous
//
#include <hip/hip_runtime.h>
#include <hip/hip_bf16.h>
#include <stdint.h>
#include <stddef.h>

typedef int i32x4 __attribute__((ext_vector_type(4)));

#define B_DIM 8192
#define K_DIM 4096
#define N_DIM 4096

typedef __attribute__((address_space(1))) const void gvoid_t;
typedef __attribute__((address_space(3))) void lvoid_t;

__device__ __forceinline__ void gload_lds16(const void* g, void* l) {
  // width-16 global->LDS DMA; LDS dest is wave-uniform base + lane*16
  __builtin_amdgcn_global_load_lds((gvoid_t*)g, (lvoid_t*)l, 16, 0, 0);
}

#define FENCE() asm volatile("" ::: "memory")
#define BARRIER() do { FENCE(); __builtin_amdgcn_s_barrier(); FENCE(); } while (0)

__device__ __forceinline__ int q8(float v, float inv) {
  float f = v * inv;
  f = fminf(fmaxf(f, -127.f), 127.f);
  return __float2int_rn(f) & 0xff;
}

// ------- kernel 1 (merged prep): row L2-norm + int8 quant for x; int8 quant W
__global__ __launch_bounds__(256) void prep_kernel(
    const float* __restrict__ x, const float* __restrict__ W,
    int8_t* __restrict__ xq, int8_t* __restrict__ wq,
    float* __restrict__ sa, float* __restrict__ sw) {
  const int t = threadIdx.x;
  const int lane = t & 63, wv = t >> 6;
  __shared__ float wsum[4], wamax[4];
  __shared__ float s_inv;

  if (blockIdx.x < B_DIM) {
    const int row = blockIdx.x;
    const float4* xr = (const float4*)(x + (size_t)row * K_DIM);
    float4 v[4];
    float ss = 0.f, am = 0.f;
#pragma unroll
    for (int i = 0; i < 4; ++i) {
      v[i] = xr[i * 256 + t];
      ss += v[i].x * v[i].x + v[i].y * v[i].y + v[i].z * v[i].z + v[i].w * v[i].w;
      am = fmaxf(am, fmaxf(fmaxf(fabsf(v[i].x), fabsf(v[i].y)),
                           fmaxf(fabsf(v[i].z), fabsf(v[i].w))));
    }
#pragma unroll
    for (int o = 32; o > 0; o >>= 1) {
      ss += __shfl_down(ss, o, 64);
      am = fmaxf(am, __shfl_down(am, o, 64));
    }
    if (lane == 0) { wsum[wv] = ss; wamax[wv] = am; }
    __syncthreads();
    if (t == 0) {
      float s = wsum[0] + wsum[1] + wsum[2] + wsum[3];
      float a = fmaxf(fmaxf(wamax[0], wamax[1]), fmaxf(wamax[2], wamax[3]));
      a = fmaxf(a, 1e-20f);
      float sc = 1.0f / (sqrtf(s) + 1e-4f);
      s_inv = 127.0f / a;            // quantization multiplier
      sa[row] = a * sc / 127.0f;     // dequant scale (includes row norm)
    }
    __syncthreads();
    const float inv = s_inv;
    uint32_t* orow = (uint32_t*)(xq + (size_t)row * K_DIM);
#pragma unroll
    for (int i = 0; i < 4; ++i) {
      uint32_t p = (uint32_t)q8(v[i].x, inv) | ((uint32_t)q8(v[i].y, inv) << 8) |
                   ((uint32_t)q8(v[i].z, inv) << 16) | ((uint32_t)q8(v[i].w, inv) << 24);
      orow[i * 256 + t] = p;
    }
  } else {
    const int row = blockIdx.x - B_DIM;   // W output-channel row
    const float4* wr = (const float4*)(W + (size_t)row * K_DIM);
    float4 v[4];
    float am = 0.f;
#pragma unroll
    for (int i = 0; i < 4; ++i) {
      v[i] = wr[i * 256 + t];
      am = fmaxf(am, fmaxf(fmaxf(fabsf(v[i].x), fabsf(v[i].y)),
                           fmaxf(fabsf(v[i].z), fabsf(v[i].w))));
    }
#pragma unroll
    for (int o = 32; o > 0; o >>= 1) am = fmaxf(am, __shfl_down(am, o, 64));
    if (lane == 0) wamax[wv] = am;
    __syncthreads();
    if (t == 0) {
      float a = fmaxf(fmaxf(wamax[0], wamax[1]), fmaxf(wamax[2], wamax[3]));
      a = fmaxf(a, 1e-20f);
      s_inv = 127.0f / a;
      sw[row] = a / 127.0f;
    }
    __syncthreads();
    const float inv = s_inv;
    uint32_t* orow = (uint32_t*)(wq + (size_t)row * K_DIM);
#pragma unroll
    for (int i = 0; i < 4; ++i) {
      uint32_t p = (uint32_t)q8(v[i].x, inv) | ((uint32_t)q8(v[i].y, inv) << 8) |
                   ((uint32_t)q8(v[i].z, inv) << 16) | ((uint32_t)q8(v[i].w, inv) << 24);
      orow[i * 256 + t] = p;
    }
  }
}

// -------- kernel 2: 256x256 int8 GEMM, C = (Aq@Wq^T)*sa*sw + b, ReLU --------
// R9 config (proven best: 147.6us): BK=128 i8 = 128B rows, XOR swizzle
// byte^=(row&7)<<4 (0 conflicts), gload_lds16 DMA, 8 waves 2Mx4N, 4-phase
// ledger + vmcnt(4) gate, 32 K-tiles.
// R11 delta: DROP the intra-phase rendezvous barrier (#1, between reads and
// MFMA). The write-hazard ledger only uses END-of-phase barriers:
//  (i) cur-B reads complete before each wave's own P2-MFMA (lgkm data-dep)
//      -> before P2-end BAR -> before P3's B(u+2) DMA issue;
//  (ii) nxt-A last read at u-1 P3, complete before u-1 P3-end BAR -> u P1 stage;
//  (iii) vmcnt(4) gate is per-wave.
// Barrier #1 was pure rendezvous: it forced all 8 waves to finish ds_reads
// before ANY entered MFMA, serializing LDS pipe vs matrix pipe (~2300cy/iter
// dead time). Without it, waves skew within a phase: one wave's MFMA overlaps
// siblings' ds_reads (m114 cross-wave MFMA||VALU mechanism).
// Failed alternatives (measured): 32x32x16 (R3), burst prefetch (R5),
// read-ahead (R6), A-in-reg (R7), balanced reads (R8 neutral), 128^2 tile (R10).
__global__ __launch_bounds__(512, 1) void gemm_kernel(
    const int8_t* __restrict__ A, const int8_t* __restrict__ Bm,
    const float* __restrict__ sa, const float* __restrict__ sw,
    const float* __restrict__ bias, float* __restrict__ C) {
  __shared__ __align__(16) char lds[131072];
  const int tid = threadIdx.x;
  const int lane = tid & 63, w = tid >> 6;
  const int wm = w >> 2, wn = w & 3;
  const int hi16 = lane >> 4;   // 0..3 (k-slot)
  const int r16 = lane & 15;

  // XCD-contiguous swizzle (512 blocks, 512 % 8 == 0 -> bijective)
  const int bid = blockIdx.x;
  const int sid = (bid & 7) * 64 + (bid >> 3);
  const int mb = sid & 31;      // 32 M-tiles
  const int nb = sid >> 5;      // 16 N-tiles

  const char* Ag = (const char*)A + (size_t)mb * 256 * K_DIM;
  const char* Bg = (const char*)Bm + (size_t)nb * 256 * K_DIM;

  auto STAGE = [&](int mat, int h, int kt) {
    const int rbase = (kt & 1) * 65536 + mat * 32768 + h * 16384;
    const char* gb = (mat == 0 ? Ag : Bg) + (size_t)h * 128 * K_DIM + kt * 128;
#pragma unroll
    for (int i = 0; i < 2; ++i) {
      const int qb = i * 8192 + w * 1024;          // wave-uniform LDS offset
      const int q = qb + lane * 16;                // this lane's linear slot
      const int r = q >> 7;                        // logical row (swizzle keeps row)
      const int cb = (q & 127) ^ ((r & 7) << 4);   // inverse-swizzled col byte
      gload_lds16(gb + (size_t)r * K_DIM + cb, lds + rbase + qb);
    }
  };
  auto LDA = [&](int m, int kq, int cur) -> i32x4 {
    const int r = m * 16 + r16;
    const int q = (r << 7) + (kq << 6) + hi16 * 16;
    return *(const i32x4*)(lds + cur * 65536 + wm * 16384 + (q ^ ((r & 7) << 4)));
  };
  auto LDB = [&](int n, int kq, int cur) -> i32x4 {
    const int r = (wn & 1) * 64 + n * 16 + r16;
    const int q = (r << 7) + (kq << 6) + hi16 * 16;
    return *(const i32x4*)(lds + cur * 65536 + 32768 + (wn >> 1) * 16384 + (q ^ ((r & 7) << 4)));
  };

  i32x4 acc[8][4] = {};
  i32x4 af[4][2], bfr[4][2];

  // prologue: A(T0).h0,h1  B(T0).h0,h1  B(T1).h0,h1 ; leave B(T1) in flight
  STAGE(0, 0, 0); STAGE(0, 1, 0); STAGE(1, 0, 0); STAGE(1, 1, 0);
  STAGE(1, 0, 1); STAGE(1, 1, 1);
  asm volatile("s_waitcnt vmcnt(4)" ::: "memory");
  BARRIER();

  for (int u = 0; u < 32; ++u) {
    const int cur = u & 1;
    const int un1 = (u + 1) & 31, un2 = (u + 2) & 31;  // wrap keeps parity, dead data
    // ---- P1: read af03 + bfr01; stage A(T_{u+1}).h0; MFMA Q00 (no rendezvous)
#pragma unroll
    for (int m = 0; m < 4; ++m)
#pragma unroll
      for (int kq = 0; kq < 2; ++kq) af[m][kq] = LDA(m, kq, cur);
#pragma unroll
    for (int n = 0; n < 2; ++n)
#pragma unroll
      for (int kq = 0; kq < 2; ++kq) bfr[n][kq] = LDB(n, kq, cur);
    STAGE(0, 0, un1);
    __builtin_amdgcn_s_setprio(1);
#pragma unroll
    for (int kq = 0; kq < 2; ++kq)
#pragma unroll
      for (int m = 0; m < 4; ++m)
#pragma unroll
        for (int n = 0; n < 2; ++n)
          acc[m][n] = __builtin_amdgcn_mfma_i32_16x16x64_i8(af[m][kq], bfr[n][kq], acc[m][n], 0, 0, 0);
    __builtin_amdgcn_s_setprio(0);
    BARRIER();
    // ---- P2: read bfr23; stage A(T_{u+1}).h1; MFMA Q01
#pragma unroll
    for (int n = 2; n < 4; ++n)
#pragma unroll
      for (int kq = 0; kq < 2; ++kq) bfr[n][kq] = LDB(n, kq, cur);
    STAGE(0, 1, un1);
    __builtin_amdgcn_s_setprio(1);
#pragma unroll
    for (int kq = 0; kq < 2; ++kq)
#pragma unroll
      for (int m = 0; m < 4; ++m)
#pragma unroll
        for (int n = 2; n < 4; ++n)
          acc[m][n] = __builtin_amdgcn_mfma_i32_16x16x64_i8(af[m][kq], bfr[n][kq], acc[m][n], 0, 0, 0);
    __builtin_amdgcn_s_setprio(0);
    BARRIER();
    // ---- P3: read af47 (overwrite af); stage B(T_{u+2}).h0; MFMA Q10
#pragma unroll
    for (int m = 0; m < 4; ++m)
#pragma unroll
      for (int kq = 0; kq < 2; ++kq) af[m][kq] = LDA(m + 4, kq, cur);
    STAGE(1, 0, un2);
    __builtin_amdgcn_s_setprio(1);
#pragma unroll
    for (int kq = 0; kq < 2; ++kq)
#pragma unroll
      for (int m = 0; m < 4; ++m)
#pragma unroll
        for (int n = 0; n < 2; ++n)
          acc[m + 4][n] = __builtin_amdgcn_mfma_i32_16x16x64_i8(af[m][kq], bfr[n][kq], acc[m + 4][n], 0, 0, 0);
    __builtin_amdgcn_s_setprio(0);
    BARRIER();
    // ---- P4: stage B(T_{u+2}).h1; MFMA Q11; counted gate vmcnt(4)
    STAGE(1, 1, un2);
    __builtin_amdgcn_s_setprio(1);
#pragma unroll
    for (int kq = 0; kq < 2; ++kq)
#pragma unroll
      for (int m = 0; m < 4; ++m)
#pragma unroll
        for (int n = 2; n < 4; ++n)
          acc[m + 4][n] = __builtin_amdgcn_mfma_i32_16x16x64_i8(af[m][kq], bfr[n][kq], acc[m + 4][n], 0, 0, 0);
    __builtin_amdgcn_s_setprio(0);
    asm volatile("s_waitcnt vmcnt(4)" ::: "memory");  // leave B(T_{u+2}) in flight only
    BARRIER();
  }

  // epilogue: y = acc * sa[row]*sw[col] + bias, ReLU, fp32 store.
  // C/D map: col=lane&15, row=(lane>>4)*4+j (dtype-independent, m121-128)
  float bv[4], sbn[4];
#pragma unroll
  for (int n = 0; n < 4; ++n) {
    const int col = nb * 256 + wn * 64 + n * 16 + r16;
    bv[n] = bias[col];
    sbn[n] = sw[col];
  }
#pragma unroll
  for (int m = 0; m < 8; ++m) {
    const int row0 = mb * 256 + wm * 128 + m * 16 + hi16 * 4;
#pragma unroll
    for (int j = 0; j < 4; ++j) {
      const float sv = sa[row0 + j];               // uniform per 16-lane group
      float* crow = C + (size_t)(row0 + j) * N_DIM + nb * 256 + wn * 64 + r16;
#pragma unroll
      for (int n = 0; n < 4; ++n)
        crow[n * 16] = fmaxf((float)acc[m][n][j] * (sv * sbn[n]) + bv[n], 0.f);
    }
  }
}

extern "C" void kernel_launch(void* const* d_in, const int* in_sizes, int n_in,
                              void* d_out, int out_size, void* d_ws, size_t ws_size,
                              hipStream_t stream) {
  const float* x = (const float*)d_in[0];
  const float* W = (const float*)d_in[1];
  const float* b = (const float*)d_in[2];
  float* out = (float*)d_out;

  int8_t* xq = (int8_t*)d_ws;                              // 32 MB
  int8_t* wq = xq + (size_t)B_DIM * K_DIM;                 // 16 MB
  float* sa = (float*)(wq + (size_t)N_DIM * K_DIM);        // 32 KB
  float* sw = sa + B_DIM;                                  // 16 KB

  // 8192 x-rows + 4096 W-rows, one block each
  prep_kernel<<<B_DIM + N_DIM, 256, 0, stream>>>(x, W, xq, wq, sa, sw);
  gemm_kernel<<<32 * 16, 512, 0, stream>>>(xq, wq, sa, sw, b, out);
}